// Round 12
// baseline (92.489 us; speedup 1.0000x reference)
//
#include <hip/hip_runtime.h>
#include <cstddef>

#define NB 2
#define RPB 4096
#define NRAY (NB*RPB)          // 8192
#define SC 48
#define SF 48
#define CP 32
#define HPX 256
#define HID 64
#define NOUT 33

#define DTC (1.05f/47.0f)
#define TC0 (2.25f + 0.5f*(1.05f/47.0f))

// d_out layout (floats)
#define OFF_DEPTH (NRAY*32)            // 262144
#define OFF_WSUM  (OFF_DEPTH + NRAY)   // 270336
#define OFF_SDF   (OFF_WSUM + NRAY)    // 278528

// ws layout (BYTES)
#define PT_B     ((size_t)0)                    // planesT f16: 25,165,824 B
#define W1A_B    ((size_t)25165824)
#define B1F_B    ((size_t)25169920)
#define W2A_B    ((size_t)25174016)
#define B2F_B    ((size_t)25180160)

#define PL_BYTES ((size_t)HPX*HPX*CP*2)         // 4,194,304 bytes per (b,pl)

typedef _Float16 f16;
typedef _Float16 f16x2 __attribute__((ext_vector_type(2)));
typedef _Float16 f16x8 __attribute__((ext_vector_type(8)));
typedef float    f32x4 __attribute__((ext_vector_type(4)));

#define LOG2E 1.44269504f
#define LN2   0.69314718f
static __device__ __forceinline__ float fast_exp(float x){
  return __builtin_amdgcn_exp2f(x*LOG2E);
}
// generic softplus (unscaled input) — used in importance/march
static __device__ __forceinline__ float softplus_f(float x){
  float e = __builtin_amdgcn_exp2f(-fabsf(x)*LOG2E);
  float l = __builtin_amdgcn_logf(1.0f + e)*LN2;
  return fmaxf(x, 0.0f) + l;
}
// pre-scaled softplus: input a' = a*log2e, returns h' = softplus(a)/ln2
static __device__ __forceinline__ float softplus_pre(float a){
  float e = __builtin_amdgcn_exp2f(-fabsf(a));
  float l = __builtin_amdgcn_logf(1.0f + e);
  return fmaxf(a, 0.0f) + l;
}
// pre-scaled sigmoid: input o' = o*log2e
static __device__ __forceinline__ float sigmoid_pre(float o){
  float e = __builtin_amdgcn_exp2f(-o);
  return __builtin_amdgcn_rcpf(1.0f + e)*1.002f - 0.001f;
}
static __device__ __forceinline__ unsigned pack2(float a, float b){
  auto h = __builtin_amdgcn_cvt_pkrtz(a, b);       // v_cvt_pkrtz_f16_f32
  return __builtin_bit_cast(unsigned int, h);
}

// per-wave slab layout (words). h buffer (P*18, words 0..1152) overlaps
// DM/SM/SRC/COEF/CDF across disjoint phases. rgbC stash: stride 14/lane.
#define SL_DM   0     // 96 f   (march)
#define SL_SM   96    // 96 f   (march)
#define SL_SRC  192   // 96 u   (march)
#define SL_COEF 288   // 96 f   (march)
#define SL_CDF  384   // 46 f   (importance)
#define SL_SIGC 1152  // 48 f
#define SL_TF   1200  // 48 f
#define SL_SIGF 1248  // 48 f
#define SL_RGBC 1344  // 64 lanes x 14 words (12 used, b64-aligned, 2-way bank)
#define SL_WORDS 2240

// planes (b,pl,c,y,x) f32 -> planesT (b,pl,y,x,c) f16; last block does frag prep
__global__ __launch_bounds__(256) void k_transpose_prep(
    const float* __restrict__ src,
    const float* __restrict__ w1, const float* __restrict__ b1,
    const float* __restrict__ w2, const float* __restrict__ b2,
    f16* __restrict__ dst,
    f16* __restrict__ w1A, float* __restrict__ b1F,
    f16* __restrict__ w2A, float* __restrict__ b2F)
{
  if (blockIdx.x == 1536){
    int tid = threadIdx.x;
    {
      int m = tid>>6, lane = tid&63, q = lane>>4, r16 = lane&15;
      #pragma unroll
      for (int j=0;j<8;j++){
        int c = q*8+j, i = m*16+r16;
        w1A[(m*64+lane)*8+j] = (f16)(w1[c*HID+i]*(LOG2E/3.0f));
      }
      #pragma unroll
      for (int r=0;r<4;r++) b1F[(m*64+lane)*4+r] = b1[m*16+q*4+r]*LOG2E;
    }
    for (int idx=tid; idx<384; idx+=256){
      int f = idx>>6, lane = idx&63, q = lane>>4, r16 = lane&15;
      int kc = f/3, m2 = f - kc*3;
      int row = m2*16+r16;
      #pragma unroll
      for (int j=0;j<8;j++){
        int k = kc*32+q*8+j;
        float v = 0.0f;
        if (row < 32)       v = w2[k*NOUT + row + 1];
        else if (row == 32) v = w2[k*NOUT + 0] * LN2;
        w2A[(f*64+lane)*8+j] = (f16)v;
      }
    }
    if (tid<192){
      int m2 = tid>>6, lane = tid&63, q = lane>>4;
      #pragma unroll
      for (int r=0;r<4;r++){
        int row = m2*16+q*4+r;
        float v = 0.0f;
        if (row < 32)       v = b2[row+1]*LOG2E;
        else if (row == 32) v = b2[0];
        b2F[(m2*64+lane)*4+r] = v;
      }
    }
    return;
  }
  int idx = blockIdx.x*256 + threadIdx.x;
  int xy = idx & (HPX*HPX-1);
  int bp = idx >> 16;
  const float* s = src + (size_t)bp*CP*HPX*HPX + xy;
  unsigned int w[16];
  #pragma unroll
  for (int c=0;c<CP;c+=2){
    w[c>>1] = pack2(s[(size_t)c*HPX*HPX], s[(size_t)(c+1)*HPX*HPX]);
  }
  uint4* d4 = reinterpret_cast<uint4*>(dst + (size_t)idx*CP);
  d4[0] = make_uint4(w[0],w[1],w[2],w[3]);
  d4[1] = make_uint4(w[4],w[5],w[6],w[7]);
  d4[2] = make_uint4(w[8],w[9],w[10],w[11]);
  d4[3] = make_uint4(w[12],w[13],w[14],w[15]);
}

// one-ray 48-point model eval: gather -> GEMM1 -> softplus' -> GEMM2.
static __device__ __forceinline__ void model48(
    const char* __restrict__ pb0,
    float ox,float oy,float oz,float dx,float dy,float dz,float t,
    const uint4* __restrict__ w1A, const f32x4* __restrict__ b1F,
    const uint4* __restrict__ w2A, const f32x4* __restrict__ b2F,
    unsigned* __restrict__ fb, float* __restrict__ fbF,
    int lane, int q, int c16,
    unsigned* rgbPk, int sigOff)
{
  unsigned wrec[3][4]; unsigned crec[3];
  {
    float cx = fmaf(t,dx,ox), cy = fmaf(t,dy,oy), cz = fmaf(t,dz,oz);
    #pragma unroll
    for (int pl=0; pl<3; pl++){
      float u = (pl==2)? cz : cx;
      float v = (pl==0)? cy : (pl==1 ? cz : cx);
      float x = ((u+1.0f)*256.0f - 1.0f)*0.5f;
      float y = ((v+1.0f)*256.0f - 1.0f)*0.5f;
      float xf = floorf(x), yf = floorf(y);
      float wx = x-xf, wy = y-yf;
      int ix = (int)xf, iy = (int)yf;
      int x0 = min(max(ix,0),HPX-1),   x1 = min(max(ix+1,0),HPX-1);
      int y0 = min(max(iy,0),HPX-1),   y1 = min(max(iy+1,0),HPX-1);
      float vx0 = ((unsigned)ix    < (unsigned)HPX) ? 1.f : 0.f;
      float vx1 = ((unsigned)(ix+1)< (unsigned)HPX) ? 1.f : 0.f;
      float vy0 = ((unsigned)iy    < (unsigned)HPX) ? 1.f : 0.f;
      float vy1 = ((unsigned)(iy+1)< (unsigned)HPX) ? 1.f : 0.f;
      float w00 = (1.f-wx)*(1.f-wy)*vx0*vy0;
      float w01 = wx*(1.f-wy)*vx1*vy0;
      float w10 = (1.f-wx)*wy*vx0*vy1;
      float w11 = wx*wy*vx1*vy1;
      wrec[pl][0] = pack2(w00,w00);
      wrec[pl][1] = pack2(w01,w01);
      wrec[pl][2] = pack2(w10,w10);
      wrec[pl][3] = pack2(w11,w11);
      crec[pl] = (unsigned)x0 | ((unsigned)x1<<8) | ((unsigned)y0<<16) | ((unsigned)y1<<24);
    }
  }

  f16x2 fs[3][4];
  #pragma unroll
  for (int s=0;s<3;s++)
    #pragma unroll
    for (int j=0;j<4;j++) fs[s][j] = (f16x2){(f16)0.0f,(f16)0.0f};

  int qoff = q*16;
  #pragma unroll
  for (int s=0;s<3;s++){
    int srcl = s*16 + c16;
    unsigned rw[12], rc[3];
    #pragma unroll
    for (int pl=0;pl<3;pl++){
      #pragma unroll
      for (int k=0;k<4;k++)
        rw[pl*4+k] = (unsigned)__shfl((int)wrec[pl][k], srcl);
      rc[pl] = (unsigned)__shfl((int)crec[pl], srcl);
    }
    int offs[12];
    #pragma unroll
    for (int pl=0;pl<3;pl++){
      unsigned crd = rc[pl];
      int x0 = crd & 255, x1 = (crd>>8) & 255;
      int y0 = (crd>>16) & 255, y1 = crd>>24;
      int pbase = (int)(pl*(int)PL_BYTES);
      offs[pl*4+0] = pbase + (y0<<14)+(x0<<6)+qoff;
      offs[pl*4+1] = pbase + (y0<<14)+(x1<<6)+qoff;
      offs[pl*4+2] = pbase + (y1<<14)+(x0<<6)+qoff;
      offs[pl*4+3] = pbase + (y1<<14)+(x1<<6)+qoff;
    }
    uint4 L[12];
    #pragma unroll
    for (int j=0;j<12;j++)
      L[j] = *reinterpret_cast<const uint4*>(pb0 + offs[j]);
    #pragma unroll
    for (int j=0;j<12;j++){
      f16x2 wv2 = __builtin_bit_cast(f16x2, rw[j]);
      fs[s][0] += __builtin_bit_cast(f16x2, L[j].x) * wv2;
      fs[s][1] += __builtin_bit_cast(f16x2, L[j].y) * wv2;
      fs[s][2] += __builtin_bit_cast(f16x2, L[j].z) * wv2;
      fs[s][3] += __builtin_bit_cast(f16x2, L[j].w) * wv2;
    }
  }

  f16x8 bfr[3];
  #pragma unroll
  for (int n=0;n<3;n++){
    uint4 u = make_uint4(__builtin_bit_cast(unsigned, fs[n][0]),
                         __builtin_bit_cast(unsigned, fs[n][1]),
                         __builtin_bit_cast(unsigned, fs[n][2]),
                         __builtin_bit_cast(unsigned, fs[n][3]));
    bfr[n] = __builtin_bit_cast(f16x8, u);
  }

  f32x4 acc2[3][3];
  #pragma unroll
  for (int m2=0;m2<3;m2++){
    f32x4 binit = b2F[m2*64+lane];
    #pragma unroll
    for (int n=0;n<3;n++) acc2[m2][n] = binit;
  }

  #pragma unroll
  for (int half=0; half<2; half++){
    // sequential A then B to cap transient accumulator pressure
    {
      f16x8 a0 = __builtin_bit_cast(f16x8, w1A[(2*half+0)*64+lane]);
      f32x4 i0 = b1F[(2*half+0)*64+lane];
      #pragma unroll
      for (int n=0;n<3;n++){
        f32x4 acc = __builtin_amdgcn_mfma_f32_16x16x32_f16(a0, bfr[n], i0, 0,0,0);
        int P = n*16 + c16;
        uint2 vA;
        vA.x = pack2(softplus_pre(acc[0]), softplus_pre(acc[1]));
        vA.y = pack2(softplus_pre(acc[2]), softplus_pre(acc[3]));
        *reinterpret_cast<uint2*>(&fb[P*18 + 0 + q*2]) = vA;
      }
    }
    {
      f16x8 a1 = __builtin_bit_cast(f16x8, w1A[(2*half+1)*64+lane]);
      f32x4 i1 = b1F[(2*half+1)*64+lane];
      #pragma unroll
      for (int n=0;n<3;n++){
        f32x4 acc = __builtin_amdgcn_mfma_f32_16x16x32_f16(a1, bfr[n], i1, 0,0,0);
        int P = n*16 + c16;
        uint2 vB;
        vB.x = pack2(softplus_pre(acc[0]), softplus_pre(acc[1]));
        vB.y = pack2(softplus_pre(acc[2]), softplus_pre(acc[3]));
        *reinterpret_cast<uint2*>(&fb[P*18 + 8 + q*2]) = vB;
      }
    }
    f16x8 b2f[3];
    #pragma unroll
    for (int n=0;n<3;n++){
      int P = n*16 + c16;
      uint4 u = *reinterpret_cast<const uint4*>(&fb[P*18 + q*4]);
      b2f[n] = __builtin_bit_cast(f16x8, u);
    }
    #pragma unroll
    for (int m2=0;m2<3;m2++){
      f16x8 a = __builtin_bit_cast(f16x8, w2A[(half*3+m2)*64+lane]);
      #pragma unroll
      for (int n=0;n<3;n++)
        acc2[m2][n] = __builtin_amdgcn_mfma_f32_16x16x32_f16(a, b2f[n], acc2[m2][n], 0,0,0);
    }
  }

  if (q==0){
    #pragma unroll
    for (int n=0;n<3;n++) fbF[sigOff + n*16 + c16] = acc2[2][n][0];
  }
  #pragma unroll
  for (int m2=0;m2<2;m2++){
    #pragma unroll
    for (int n=0;n<3;n++){
      f32x4 v = acc2[m2][n];
      rgbPk[(m2*3+n)*2+0] = pack2(sigmoid_pre(v[0]), sigmoid_pre(v[1]));
      rgbPk[(m2*3+n)*2+1] = pack2(sigmoid_pre(v[2]), sigmoid_pre(v[3]));
    }
  }
}

// one wave = one ray; force total reg budget <= 170 (3 waves/SIMD)
__global__ __launch_bounds__(256, 3) void k_render(
    const f16* __restrict__ pT,
    const float* __restrict__ orig,
    const float* __restrict__ dirs,
    const uint4* __restrict__ w1A,
    const f32x4* __restrict__ b1F,
    const uint4* __restrict__ w2A,
    const f32x4* __restrict__ b2F,
    float* __restrict__ out)
{
  __shared__ unsigned int lds[4][SL_WORDS];
  int tid = threadIdx.x;
  int lane = tid & 63;
  int wv = tid >> 6;
  int ray = blockIdx.x*4 + wv;
  unsigned* S = &lds[wv][0];
  float* Sf = (float*)S;
  int q = lane >> 4;
  int c16 = lane & 15;

  int bb = ray >> 12;
  const char* pb0 = (const char*)pT + (size_t)(bb*3)*PL_BYTES;
  float ox = orig[ray*3+0], oy = orig[ray*3+1], oz = orig[ray*3+2];
  float dx = dirs[ray*3+0], dy = dirs[ray*3+1], dz = dirs[ray*3+2];

  // ---- coarse pass; rgb stashed to LDS to free registers across later phases
  {
    unsigned rgbC[12];
    float tC = TC0 + (float)min(lane,47)*DTC;
    model48(pb0, ox,oy,oz,dx,dy,dz, tC, w1A,b1F,w2A,b2F, S, Sf, lane,q,c16, rgbC, SL_SIGC);
    int rb = SL_RGBC + lane*14;
    #pragma unroll
    for (int i=0;i<6;i++)
      *reinterpret_cast<uint2*>(&S[rb + 2*i]) = make_uint2(rgbC[2*i], rgbC[2*i+1]);
  }
  if (lane < 48) out[OFF_SDF + (size_t)ray*48 + lane] = Sf[SL_SIGC+lane];

  // ---- importance resample (wave-parallel) ----
  {
    float sk  = Sf[SL_SIGC + min(lane,47)];
    float sk1 = Sf[SL_SIGC + min(lane+1,47)];
    float alpha = 0.f, g = 1.f;
    if (lane < 47){
      float dm = softplus_f(0.5f*(sk+sk1)-1.0f);
      alpha = 1.0f - fast_exp(-dm*DTC);
      g = 1.0f - alpha + 1e-10f;
    }
    float ip = g;
    #pragma unroll
    for (int off=1; off<64; off<<=1){ float v=__shfl_up(ip,off); if(lane>=off) ip*=v; }
    float T = __shfl_up(ip,1); if (lane==0) T = 1.0f;
    float wk = alpha*T;
    float wm1 = __shfl_up(wk,1);   if (lane==0) wm1 = 0.f;
    float wp1 = __shfl_down(wk,1);
    float qv = 0.5f*(fmaxf(wm1,wk)+fmaxf(wk,wp1)) + 0.01f;
    float qs = (lane>=1 && lane<=45)? qv : 0.0f;
    float sum = qs;
    #pragma unroll
    for (int off=1; off<64; off<<=1) sum += __shfl_xor(sum,off);
    float cs = qs;
    #pragma unroll
    for (int off=1; off<64; off<<=1){ float v=__shfl_up(cs,off); if(lane>=off) cs+=v; }
    float C = cs/sum;
    if (lane < 46) Sf[SL_CDF+lane] = C;
    float u = (float)lane/47.0f;
    int pos = 0;
    #pragma unroll
    for (int st=32; st>=1; st>>=1){
      int np = pos+st;
      if (np<=45 && Sf[SL_CDF+np] <= u) pos = np;
    }
    int ab = min(pos+1,45);
    float cb = Sf[SL_CDF+pos];
    float ca = Sf[SL_CDF+ab];
    float bbz = TC0 + ((float)pos+0.5f)*DTC;
    float baz = TC0 + ((float)ab +0.5f)*DTC;
    float denom = ca - cb;
    if (denom < 1e-5f) denom = 1.0f;
    float tf = bbz + (u-cb)/denom*(baz-bbz);
    if (lane < 48) Sf[SL_TF+lane] = tf;
  }

  // ---- fine pass ----
  unsigned rgbF[12];
  float tF = Sf[SL_TF + min(lane,47)];
  model48(pb0, ox,oy,oz,dx,dy,dz, tF, w1A,b1F,w2A,b2F, S, Sf, lane,q,c16, rgbF, SL_SIGF);

  // ---- merge ranks (stable: coarse first on tie) ----
  if (lane < 48){
    float dcv = TC0 + (float)lane*DTC;
    int pos = 0;
    #pragma unroll
    for (int stp=32; stp>=1; stp>>=1){
      int np = pos + stp;
      if (np <= 48 && Sf[SL_TF+np-1] < dcv) pos = np;
    }
    int rank_c = lane + pos;
    Sf[SL_DM+rank_c] = dcv;
    Sf[SL_SM+rank_c] = Sf[SL_SIGC+lane];
    S [SL_SRC+rank_c] = lane;
    float x = Sf[SL_TF+lane];
    int cnt = (int)(floorf((x - TC0)*(1.0f/DTC)) + 1.0f);
    cnt = min(max(cnt,0),48);
    while (cnt < 48 && (TC0 + (float)cnt*DTC) <= x) cnt++;
    while (cnt > 0 && (TC0 + (float)(cnt-1)*DTC) > x) cnt--;
    int rank_f = lane + cnt;
    Sf[SL_DM+rank_f] = x;
    Sf[SL_SM+rank_f] = Sf[SL_SIGF+lane];
    S [SL_SRC+rank_f] = 48 + lane;
  }

  // ---- march ----
  int s0 = 2*lane, s1 = s0+1;
  float alpha0=0.f, alpha1=0.f, g0=1.f, g1=1.f;
  float d0=0.f, d1=0.f, d2=0.f;
  if (lane < 48){
    int s2i = min(s1+1, 95);
    d0 = Sf[SL_DM+s0]; d1 = Sf[SL_DM+s1]; d2 = Sf[SL_DM+s2i];
    float m0 = Sf[SL_SM+s0], m1 = Sf[SL_SM+s1], m2v = Sf[SL_SM+s2i];
    {
      float dm = softplus_f(0.5f*(m0+m1)-1.0f);
      alpha0 = 1.0f - fast_exp(-dm*(d1-d0));
      g0 = 1.0f - alpha0 + 1e-10f;
    }
    if (lane < 47){
      float dm = softplus_f(0.5f*(m1+m2v)-1.0f);
      alpha1 = 1.0f - fast_exp(-dm*(d2-d1));
      g1 = 1.0f - alpha1 + 1e-10f;
    }
  }
  float ip = g0*g1;
  #pragma unroll
  for (int off=1; off<64; off<<=1){
    float v = __shfl_up(ip, off);
    if (lane >= off) ip *= v;
  }
  float E = __shfl_up(ip, 1);
  if (lane == 0) E = 1.0f;
  float w0 = alpha0*E;
  float w1v = alpha1*E*g0;
  float wprev = __shfl_up(w1v, 1);
  if (lane == 0) wprev = 0.0f;
  float coef0 = 0.5f*(wprev + w0);
  float coef1 = 0.5f*(w0 + w1v);
  float dp = (lane<48) ? (w0*0.5f*(d0+d1) + w1v*0.5f*(d1+d2)) : 0.f;
  float wp = w0 + w1v;

  if (lane < 48){
    int src0 = (int)S[SL_SRC+s0], src1 = (int)S[SL_SRC+s1];
    Sf[SL_COEF+src0] = coef0;
    Sf[SL_COEF+src1] = coef1;
  }

  #pragma unroll
  for (int off=1; off<64; off<<=1){
    dp += __shfl_xor(dp, off);
    wp += __shfl_xor(wp, off);
  }

  // ---- color sum in MFMA C-layout, reduce over c16 ----
  unsigned rgbC[12];
  {
    int rb = SL_RGBC + lane*14;
    #pragma unroll
    for (int i=0;i<6;i++){
      uint2 v = *reinterpret_cast<const uint2*>(&S[rb + 2*i]);
      rgbC[2*i] = v.x; rgbC[2*i+1] = v.y;
    }
  }
  float cc[8] = {0.f,0.f,0.f,0.f,0.f,0.f,0.f,0.f};
  #pragma unroll
  for (int n=0;n<3;n++){
    int pt = n*16 + c16;
    float cfC = Sf[SL_COEF + pt];
    float cfF = Sf[SL_COEF + 48 + pt];
    #pragma unroll
    for (int m2=0;m2<2;m2++){
      #pragma unroll
      for (int hw=0; hw<2; hw++){
        f16x2 hc = __builtin_bit_cast(f16x2, rgbC[(m2*3+n)*2+hw]);
        f16x2 hf = __builtin_bit_cast(f16x2, rgbF[(m2*3+n)*2+hw]);
        cc[m2*4+hw*2+0] += cfC*(float)hc[0] + cfF*(float)hf[0];
        cc[m2*4+hw*2+1] += cfC*(float)hc[1] + cfF*(float)hf[1];
      }
    }
  }
  #pragma unroll
  for (int off=1; off<16; off<<=1){
    #pragma unroll
    for (int i=0;i<8;i++) cc[i] += __shfl_xor(cc[i], off);
  }
  if (c16 == 0){
    #pragma unroll
    for (int m2=0;m2<2;m2++){
      f32x4 o4;
      #pragma unroll
      for (int r=0;r<4;r++) o4[r] = 2.0f*cc[m2*4+r] - 1.0f;
      *reinterpret_cast<f32x4*>(&out[(size_t)ray*32 + m2*16 + q*4]) = o4;
    }
  }
  if (lane == 0){
    out[OFF_DEPTH+ray] = dp;
    out[OFF_WSUM+ray]  = wp;
  }
}

extern "C" void kernel_launch(void* const* d_in, const int* in_sizes, int n_in,
                              void* d_out, int out_size, void* d_ws, size_t ws_size,
                              hipStream_t stream){
  const float* planes = (const float*)d_in[0];
  const float* orig   = (const float*)d_in[1];
  const float* dirs   = (const float*)d_in[2];
  const float* w1     = (const float*)d_in[3];
  const float* b1     = (const float*)d_in[4];
  const float* w2     = (const float*)d_in[5];
  const float* b2     = (const float*)d_in[6];
  float* out = (float*)d_out;
  char*  ws  = (char*)d_ws;

  f16*   pT    = (f16*)(ws + PT_B);
  f16*   w1A   = (f16*)(ws + W1A_B);
  float* b1F   = (float*)(ws + B1F_B);
  f16*   w2A   = (f16*)(ws + W2A_B);
  float* b2F   = (float*)(ws + B2F_B);

  k_transpose_prep<<<dim3(1537), dim3(256), 0, stream>>>(
      planes, w1, b1, w2, b2, pT, w1A, b1F, w2A, b2F);
  k_render<<<dim3(NRAY/4), dim3(256), 0, stream>>>(
      pT, orig, dirs, (const uint4*)w1A, (const f32x4*)b1F,
      (const uint4*)w2A, (const f32x4*)b2F, out);
}

// Round 13
// 90.101 us; speedup vs baseline: 1.0265x; 1.0265x over previous
//
#include <hip/hip_runtime.h>
#include <cstddef>

#define NB 2
#define RPB 4096
#define NRAY (NB*RPB)          // 8192
#define SC 48
#define SF 48
#define CP 32
#define HPX 256
#define HID 64
#define NOUT 33

#define DTC (1.05f/47.0f)
#define TC0 (2.25f + 0.5f*(1.05f/47.0f))

// d_out layout (floats)
#define OFF_DEPTH (NRAY*32)            // 262144
#define OFF_WSUM  (OFF_DEPTH + NRAY)   // 270336
#define OFF_SDF   (OFF_WSUM + NRAY)    // 278528

// ws layout (BYTES)
#define PT_B     ((size_t)0)                    // planesT f16: 25,165,824 B
#define W1A_B    ((size_t)25165824)
#define B1F_B    ((size_t)25169920)
#define W2A_B    ((size_t)25174016)
#define B2F_B    ((size_t)25180160)

#define PL_BYTES ((size_t)HPX*HPX*CP*2)         // 4,194,304 bytes per (b,pl)

typedef _Float16 f16;
typedef _Float16 f16x2 __attribute__((ext_vector_type(2)));
typedef _Float16 f16x8 __attribute__((ext_vector_type(8)));
typedef float    f32x4 __attribute__((ext_vector_type(4)));

#define LOG2E 1.44269504f
#define LN2   0.69314718f
static __device__ __forceinline__ float fast_exp(float x){
  return __builtin_amdgcn_exp2f(x*LOG2E);
}
static __device__ __forceinline__ float softplus_f(float x){
  float e = __builtin_amdgcn_exp2f(-fabsf(x)*LOG2E);
  float l = __builtin_amdgcn_logf(1.0f + e)*LN2;
  return fmaxf(x, 0.0f) + l;
}
static __device__ __forceinline__ float fast_sigmoid_scaled(float a){
  float e = __builtin_amdgcn_exp2f(-a*LOG2E);
  return __builtin_amdgcn_rcpf(1.0f + e)*1.002f - 0.001f;
}
static __device__ __forceinline__ unsigned pack2(float a, float b){
  f16x2 h = { (f16)a, (f16)b };
  return __builtin_bit_cast(unsigned int, h);
}

// per-wave slab layout (words)
#define SL_DM   0     // 96 f
#define SL_SM   96    // 96 f
#define SL_SRC  192   // 96 u
#define SL_COEF 288   // 96 f
#define SL_CDF  384   // 46 f
#define SL_SIGC 1152  // 48 f
#define SL_TF   1200  // 48 f
#define SL_SIGF 1248  // 48 f
#define SL_WORDS 1344

// planes (b,pl,c,y,x) f32 -> planesT (b,pl,y,x,c) f16; last block does frag prep
__global__ __launch_bounds__(256) void k_transpose_prep(
    const float* __restrict__ src,
    const float* __restrict__ w1, const float* __restrict__ b1,
    const float* __restrict__ w2, const float* __restrict__ b2,
    f16* __restrict__ dst,
    f16* __restrict__ w1A, float* __restrict__ b1F,
    f16* __restrict__ w2A, float* __restrict__ b2F)
{
  if (blockIdx.x == 1536){
    int tid = threadIdx.x;
    {
      int m = tid>>6, lane = tid&63, q = lane>>4, r16 = lane&15;
      #pragma unroll
      for (int j=0;j<8;j++){
        int c = q*8+j, i = m*16+r16;
        w1A[(m*64+lane)*8+j] = (f16)(w1[c*HID+i]*(1.0f/3.0f));
      }
      #pragma unroll
      for (int r=0;r<4;r++) b1F[(m*64+lane)*4+r] = b1[m*16+q*4+r];
    }
    for (int idx=tid; idx<384; idx+=256){
      int f = idx>>6, lane = idx&63, q = lane>>4, r16 = lane&15;
      int kc = f/3, m2 = f - kc*3;
      int row = m2*16+r16;
      int col = (row<32)? (row+1) : ((row==32)? 0 : -1);
      #pragma unroll
      for (int j=0;j<8;j++){
        int k = kc*32+q*8+j;
        w2A[(f*64+lane)*8+j] = (col>=0)? (f16)w2[k*NOUT+col] : (f16)0.0f;
      }
    }
    if (tid<192){
      int m2 = tid>>6, lane = tid&63, q = lane>>4;
      #pragma unroll
      for (int r=0;r<4;r++){
        int row = m2*16+q*4+r;
        float v = (row<32)? b2[row+1] : ((row==32)? b2[0] : 0.0f);
        b2F[(m2*64+lane)*4+r] = v;
      }
    }
    return;
  }
  int idx = blockIdx.x*256 + threadIdx.x;
  int xy = idx & (HPX*HPX-1);
  int bp = idx >> 16;
  const float* s = src + (size_t)bp*CP*HPX*HPX + xy;
  unsigned int w[16];
  #pragma unroll
  for (int c=0;c<CP;c+=2){
    w[c>>1] = pack2(s[(size_t)c*HPX*HPX], s[(size_t)(c+1)*HPX*HPX]);
  }
  uint4* d4 = reinterpret_cast<uint4*>(dst + (size_t)idx*CP);
  d4[0] = make_uint4(w[0],w[1],w[2],w[3]);
  d4[1] = make_uint4(w[4],w[5],w[6],w[7]);
  d4[2] = make_uint4(w[8],w[9],w[10],w[11]);
  d4[3] = make_uint4(w[12],w[13],w[14],w[15]);
}

// one-ray 48-point model eval: gather -> GEMM1 -> softplus -> GEMM2.
static __device__ __forceinline__ void model48(
    const char* __restrict__ pb0,
    float ox,float oy,float oz,float dx,float dy,float dz,float t,
    const uint4* __restrict__ w1A, const f32x4* __restrict__ b1F,
    const uint4* __restrict__ w2A, const f32x4* __restrict__ b2F,
    unsigned* __restrict__ fb, float* __restrict__ fbF,
    int lane, int q, int c16,
    unsigned* rgbPk, int sigOff)
{
  unsigned wrec[3][4]; unsigned crec[3];
  {
    float cx = fmaf(t,dx,ox), cy = fmaf(t,dy,oy), cz = fmaf(t,dz,oz);
    #pragma unroll
    for (int pl=0; pl<3; pl++){
      float u = (pl==2)? cz : cx;
      float v = (pl==0)? cy : (pl==1 ? cz : cx);
      float x = ((u+1.0f)*256.0f - 1.0f)*0.5f;
      float y = ((v+1.0f)*256.0f - 1.0f)*0.5f;
      float xf = floorf(x), yf = floorf(y);
      float wx = x-xf, wy = y-yf;
      int ix = (int)xf, iy = (int)yf;
      int x0 = min(max(ix,0),HPX-1),   x1 = min(max(ix+1,0),HPX-1);
      int y0 = min(max(iy,0),HPX-1),   y1 = min(max(iy+1,0),HPX-1);
      float vx0 = ((unsigned)ix    < (unsigned)HPX) ? 1.f : 0.f;
      float vx1 = ((unsigned)(ix+1)< (unsigned)HPX) ? 1.f : 0.f;
      float vy0 = ((unsigned)iy    < (unsigned)HPX) ? 1.f : 0.f;
      float vy1 = ((unsigned)(iy+1)< (unsigned)HPX) ? 1.f : 0.f;
      float w00 = (1.f-wx)*(1.f-wy)*vx0*vy0;
      float w01 = wx*(1.f-wy)*vx1*vy0;
      float w10 = (1.f-wx)*wy*vx0*vy1;
      float w11 = wx*wy*vx1*vy1;
      wrec[pl][0] = pack2(w00,w00);
      wrec[pl][1] = pack2(w01,w01);
      wrec[pl][2] = pack2(w10,w10);
      wrec[pl][3] = pack2(w11,w11);
      crec[pl] = (unsigned)x0 | ((unsigned)x1<<8) | ((unsigned)y0<<16) | ((unsigned)y1<<24);
    }
  }

  f16x2 fs[3][4];
  #pragma unroll
  for (int s=0;s<3;s++)
    #pragma unroll
    for (int j=0;j<4;j++) fs[s][j] = (f16x2){(f16)0.0f,(f16)0.0f};

  int qoff = q*16;
  #pragma unroll
  for (int s=0;s<3;s++){
    int srcl = s*16 + c16;
    unsigned rw[12], rc[3];
    #pragma unroll
    for (int pl=0;pl<3;pl++){
      #pragma unroll
      for (int k=0;k<4;k++)
        rw[pl*4+k] = (unsigned)__shfl((int)wrec[pl][k], srcl);
      rc[pl] = (unsigned)__shfl((int)crec[pl], srcl);
    }
    int offs[12];
    #pragma unroll
    for (int pl=0;pl<3;pl++){
      unsigned crd = rc[pl];
      int x0 = crd & 255, x1 = (crd>>8) & 255;
      int y0 = (crd>>16) & 255, y1 = crd>>24;
      int pbase = (int)(pl*(int)PL_BYTES);
      offs[pl*4+0] = pbase + (y0<<14)+(x0<<6)+qoff;
      offs[pl*4+1] = pbase + (y0<<14)+(x1<<6)+qoff;
      offs[pl*4+2] = pbase + (y1<<14)+(x0<<6)+qoff;
      offs[pl*4+3] = pbase + (y1<<14)+(x1<<6)+qoff;
    }
    uint4 L[12];
    #pragma unroll
    for (int j=0;j<12;j++)
      L[j] = *reinterpret_cast<const uint4*>(pb0 + offs[j]);
    #pragma unroll
    for (int j=0;j<12;j++){
      f16x2 wv2 = __builtin_bit_cast(f16x2, rw[j]);
      fs[s][0] += __builtin_bit_cast(f16x2, L[j].x) * wv2;
      fs[s][1] += __builtin_bit_cast(f16x2, L[j].y) * wv2;
      fs[s][2] += __builtin_bit_cast(f16x2, L[j].z) * wv2;
      fs[s][3] += __builtin_bit_cast(f16x2, L[j].w) * wv2;
    }
  }

  f16x8 bfr[3];
  #pragma unroll
  for (int n=0;n<3;n++){
    uint4 u = make_uint4(__builtin_bit_cast(unsigned, fs[n][0]),
                         __builtin_bit_cast(unsigned, fs[n][1]),
                         __builtin_bit_cast(unsigned, fs[n][2]),
                         __builtin_bit_cast(unsigned, fs[n][3]));
    bfr[n] = __builtin_bit_cast(f16x8, u);
  }

  f32x4 acc2[3][3];
  #pragma unroll
  for (int m2=0;m2<3;m2++){
    f32x4 binit = b2F[m2*64+lane];
    #pragma unroll
    for (int n=0;n<3;n++) acc2[m2][n] = binit;
  }

  #pragma unroll
  for (int half=0; half<2; half++){
    f16x8 a0 = __builtin_bit_cast(f16x8, w1A[(2*half+0)*64+lane]);
    f16x8 a1 = __builtin_bit_cast(f16x8, w1A[(2*half+1)*64+lane]);
    f32x4 i0 = b1F[(2*half+0)*64+lane];
    f32x4 i1 = b1F[(2*half+1)*64+lane];
    f32x4 accA[3], accB[3];
    #pragma unroll
    for (int n=0;n<3;n++){
      accA[n] = __builtin_amdgcn_mfma_f32_16x16x32_f16(a0, bfr[n], i0, 0,0,0);
      accB[n] = __builtin_amdgcn_mfma_f32_16x16x32_f16(a1, bfr[n], i1, 0,0,0);
    }
    #pragma unroll
    for (int n=0;n<3;n++){
      int P = n*16 + c16;
      uint2 vA, vB;
      vA.x = pack2(softplus_f(accA[n][0]), softplus_f(accA[n][1]));
      vA.y = pack2(softplus_f(accA[n][2]), softplus_f(accA[n][3]));
      vB.x = pack2(softplus_f(accB[n][0]), softplus_f(accB[n][1]));
      vB.y = pack2(softplus_f(accB[n][2]), softplus_f(accB[n][3]));
      *reinterpret_cast<uint2*>(&fb[P*18 + 0 + q*2]) = vA;
      *reinterpret_cast<uint2*>(&fb[P*18 + 8 + q*2]) = vB;
    }
    f16x8 b2f[3];
    #pragma unroll
    for (int n=0;n<3;n++){
      int P = n*16 + c16;
      uint4 u = *reinterpret_cast<const uint4*>(&fb[P*18 + q*4]);
      b2f[n] = __builtin_bit_cast(f16x8, u);
    }
    #pragma unroll
    for (int m2=0;m2<3;m2++){
      f16x8 a = __builtin_bit_cast(f16x8, w2A[(half*3+m2)*64+lane]);
      #pragma unroll
      for (int n=0;n<3;n++)
        acc2[m2][n] = __builtin_amdgcn_mfma_f32_16x16x32_f16(a, b2f[n], acc2[m2][n], 0,0,0);
    }
  }

  if (q==0){
    #pragma unroll
    for (int n=0;n<3;n++) fbF[sigOff + n*16 + c16] = acc2[2][n][0];
  }
  #pragma unroll
  for (int m2=0;m2<2;m2++){
    #pragma unroll
    for (int n=0;n<3;n++){
      f32x4 v = acc2[m2][n];
      rgbPk[(m2*3+n)*2+0] = pack2(fast_sigmoid_scaled(v[0]), fast_sigmoid_scaled(v[1]));
      rgbPk[(m2*3+n)*2+1] = pack2(fast_sigmoid_scaled(v[2]), fast_sigmoid_scaled(v[3]));
    }
  }
}

// one wave = one ray
__global__ __launch_bounds__(256, 2) void k_render(
    const f16* __restrict__ pT,
    const float* __restrict__ orig,
    const float* __restrict__ dirs,
    const uint4* __restrict__ w1A,
    const f32x4* __restrict__ b1F,
    const uint4* __restrict__ w2A,
    const f32x4* __restrict__ b2F,
    float* __restrict__ out)
{
  __shared__ unsigned int lds[4][SL_WORDS];
  int tid = threadIdx.x;
  int lane = tid & 63;
  int wv = tid >> 6;
  int ray = blockIdx.x*4 + wv;
  unsigned* S = &lds[wv][0];
  float* Sf = (float*)S;
  int q = lane >> 4;
  int c16 = lane & 15;

  int bb = ray >> 12;
  const char* pb0 = (const char*)pT + (size_t)(bb*3)*PL_BYTES;
  float ox = orig[ray*3+0], oy = orig[ray*3+1], oz = orig[ray*3+2];
  float dx = dirs[ray*3+0], dy = dirs[ray*3+1], dz = dirs[ray*3+2];

  unsigned rgbC[12], rgbF[12];

  // ---- coarse pass ----
  float tC = TC0 + (float)min(lane,47)*DTC;
  model48(pb0, ox,oy,oz,dx,dy,dz, tC, w1A,b1F,w2A,b2F, S, Sf, lane,q,c16, rgbC, SL_SIGC);
  if (lane < 48) out[OFF_SDF + (size_t)ray*48 + lane] = Sf[SL_SIGC+lane];

  // ---- importance resample (wave-parallel) ----
  {
    float sk  = Sf[SL_SIGC + min(lane,47)];
    float sk1 = Sf[SL_SIGC + min(lane+1,47)];
    float alpha = 0.f, g = 1.f;
    if (lane < 47){
      float dm = softplus_f(0.5f*(sk+sk1)-1.0f);
      alpha = 1.0f - fast_exp(-dm*DTC);
      g = 1.0f - alpha + 1e-10f;
    }
    float ip = g;
    #pragma unroll
    for (int off=1; off<64; off<<=1){ float v=__shfl_up(ip,off); if(lane>=off) ip*=v; }
    float T = __shfl_up(ip,1); if (lane==0) T = 1.0f;
    float wk = alpha*T;
    float wm1 = __shfl_up(wk,1);   if (lane==0) wm1 = 0.f;
    float wp1 = __shfl_down(wk,1);
    float qv = 0.5f*(fmaxf(wm1,wk)+fmaxf(wk,wp1)) + 0.01f;
    float qs = (lane>=1 && lane<=45)? qv : 0.0f;
    float sum = qs;
    #pragma unroll
    for (int off=1; off<64; off<<=1) sum += __shfl_xor(sum,off);
    float cs = qs;
    #pragma unroll
    for (int off=1; off<64; off<<=1){ float v=__shfl_up(cs,off); if(lane>=off) cs+=v; }
    float C = cs/sum;
    if (lane < 46) Sf[SL_CDF+lane] = C;
    float u = (float)lane/47.0f;
    int pos = 0;
    #pragma unroll
    for (int st=32; st>=1; st>>=1){
      int np = pos+st;
      if (np<=45 && Sf[SL_CDF+np] <= u) pos = np;
    }
    int ab = min(pos+1,45);
    float cb = Sf[SL_CDF+pos];
    float ca = Sf[SL_CDF+ab];
    float bbz = TC0 + ((float)pos+0.5f)*DTC;
    float baz = TC0 + ((float)ab +0.5f)*DTC;
    float denom = ca - cb;
    if (denom < 1e-5f) denom = 1.0f;
    float tf = bbz + (u-cb)/denom*(baz-bbz);
    if (lane < 48) Sf[SL_TF+lane] = tf;
  }

  // ---- fine pass ----
  float tF = Sf[SL_TF + min(lane,47)];
  model48(pb0, ox,oy,oz,dx,dy,dz, tF, w1A,b1F,w2A,b2F, S, Sf, lane,q,c16, rgbF, SL_SIGF);

  // ---- merge ranks (stable: coarse first on tie) ----
  if (lane < 48){
    float dcv = TC0 + (float)lane*DTC;
    int pos = 0;
    #pragma unroll
    for (int stp=32; stp>=1; stp>>=1){
      int np = pos + stp;
      if (np <= 48 && Sf[SL_TF+np-1] < dcv) pos = np;
    }
    int rank_c = lane + pos;
    Sf[SL_DM+rank_c] = dcv;
    Sf[SL_SM+rank_c] = Sf[SL_SIGC+lane];
    S [SL_SRC+rank_c] = lane;
    float x = Sf[SL_TF+lane];
    int cnt = (int)(floorf((x - TC0)*(1.0f/DTC)) + 1.0f);
    cnt = min(max(cnt,0),48);
    while (cnt < 48 && (TC0 + (float)cnt*DTC) <= x) cnt++;
    while (cnt > 0 && (TC0 + (float)(cnt-1)*DTC) > x) cnt--;
    int rank_f = lane + cnt;
    Sf[SL_DM+rank_f] = x;
    Sf[SL_SM+rank_f] = Sf[SL_SIGF+lane];
    S [SL_SRC+rank_f] = 48 + lane;
  }

  // ---- march ----
  int s0 = 2*lane, s1 = s0+1;
  float alpha0=0.f, alpha1=0.f, g0=1.f, g1=1.f;
  float d0=0.f, d1=0.f, d2=0.f;
  if (lane < 48){
    int s2i = min(s1+1, 95);
    d0 = Sf[SL_DM+s0]; d1 = Sf[SL_DM+s1]; d2 = Sf[SL_DM+s2i];
    float m0 = Sf[SL_SM+s0], m1 = Sf[SL_SM+s1], m2v = Sf[SL_SM+s2i];
    {
      float dm = softplus_f(0.5f*(m0+m1)-1.0f);
      alpha0 = 1.0f - fast_exp(-dm*(d1-d0));
      g0 = 1.0f - alpha0 + 1e-10f;
    }
    if (lane < 47){
      float dm = softplus_f(0.5f*(m1+m2v)-1.0f);
      alpha1 = 1.0f - fast_exp(-dm*(d2-d1));
      g1 = 1.0f - alpha1 + 1e-10f;
    }
  }
  float ip = g0*g1;
  #pragma unroll
  for (int off=1; off<64; off<<=1){
    float v = __shfl_up(ip, off);
    if (lane >= off) ip *= v;
  }
  float E = __shfl_up(ip, 1);
  if (lane == 0) E = 1.0f;
  float w0 = alpha0*E;
  float w1v = alpha1*E*g0;
  float wprev = __shfl_up(w1v, 1);
  if (lane == 0) wprev = 0.0f;
  float coef0 = 0.5f*(wprev + w0);
  float coef1 = 0.5f*(w0 + w1v);
  float dp = (lane<48) ? (w0*0.5f*(d0+d1) + w1v*0.5f*(d1+d2)) : 0.f;
  float wp = w0 + w1v;

  if (lane < 48){
    int src0 = (int)S[SL_SRC+s0], src1 = (int)S[SL_SRC+s1];
    Sf[SL_COEF+src0] = coef0;
    Sf[SL_COEF+src1] = coef1;
  }

  #pragma unroll
  for (int off=1; off<64; off<<=1){
    dp += __shfl_xor(dp, off);
    wp += __shfl_xor(wp, off);
  }

  // ---- color sum in MFMA C-layout, reduce over c16 ----
  float cc[8] = {0.f,0.f,0.f,0.f,0.f,0.f,0.f,0.f};
  #pragma unroll
  for (int n=0;n<3;n++){
    int pt = n*16 + c16;
    float cfC = Sf[SL_COEF + pt];
    float cfF = Sf[SL_COEF + 48 + pt];
    #pragma unroll
    for (int m2=0;m2<2;m2++){
      #pragma unroll
      for (int hw=0; hw<2; hw++){
        f16x2 hc = __builtin_bit_cast(f16x2, rgbC[(m2*3+n)*2+hw]);
        f16x2 hf = __builtin_bit_cast(f16x2, rgbF[(m2*3+n)*2+hw]);
        cc[m2*4+hw*2+0] += cfC*(float)hc[0] + cfF*(float)hf[0];
        cc[m2*4+hw*2+1] += cfC*(float)hc[1] + cfF*(float)hf[1];
      }
    }
  }
  #pragma unroll
  for (int off=1; off<16; off<<=1){
    #pragma unroll
    for (int i=0;i<8;i++) cc[i] += __shfl_xor(cc[i], off);
  }
  if (c16 == 0){
    #pragma unroll
    for (int m2=0;m2<2;m2++){
      f32x4 o4;
      #pragma unroll
      for (int r=0;r<4;r++) o4[r] = 2.0f*cc[m2*4+r] - 1.0f;
      *reinterpret_cast<f32x4*>(&out[(size_t)ray*32 + m2*16 + q*4]) = o4;
    }
  }
  if (lane == 0){
    out[OFF_DEPTH+ray] = dp;
    out[OFF_WSUM+ray]  = wp;
  }
}

extern "C" void kernel_launch(void* const* d_in, const int* in_sizes, int n_in,
                              void* d_out, int out_size, void* d_ws, size_t ws_size,
                              hipStream_t stream){
  const float* planes = (const float*)d_in[0];
  const float* orig   = (const float*)d_in[1];
  const float* dirs   = (const float*)d_in[2];
  const float* w1     = (const float*)d_in[3];
  const float* b1     = (const float*)d_in[4];
  const float* w2     = (const float*)d_in[5];
  const float* b2     = (const float*)d_in[6];
  float* out = (float*)d_out;
  char*  ws  = (char*)d_ws;

  f16*   pT    = (f16*)(ws + PT_B);
  f16*   w1A   = (f16*)(ws + W1A_B);
  float* b1F   = (float*)(ws + B1F_B);
  f16*   w2A   = (f16*)(ws + W2A_B);
  float* b2F   = (float*)(ws + B2F_B);

  k_transpose_prep<<<dim3(1537), dim3(256), 0, stream>>>(
      planes, w1, b1, w2, b2, pT, w1A, b1F, w2A, b2F);
  k_render<<<dim3(NRAY/4), dim3(256), 0, stream>>>(
      pT, orig, dirs, (const uint4*)w1A, (const f32x4*)b1F,
      (const uint4*)w2A, (const f32x4*)b2F, out);
}